// Round 1
// baseline (2141.628 us; speedup 1.0000x reference)
//
#include <hip/hip_runtime.h>
#include <hip/hip_bf16.h>

// Problem constants (from reference)
//   N_NODES=50000, N_EDGES=800000, IN=128, HID=128, OUT=64, fp32 everywhere.

__global__ void k_init_deg(float* __restrict__ deg, int n) {
    int i = blockIdx.x * blockDim.x + threadIdx.x;
    if (i < n) deg[i] = 1.0f;  // self-loop contributes 1 to every node
}

__global__ void k_deg_accum(const int* __restrict__ dst, float* __restrict__ deg, int e) {
    int i = blockIdx.x * blockDim.x + threadIdx.x;
    if (i < e) atomicAdd(&deg[dst[i]], 1.0f);
}

__global__ void k_dinv(const float* __restrict__ deg, float* __restrict__ dinv,
                       float* __restrict__ dinv2, int n) {
    int i = blockIdx.x * blockDim.x + threadIdx.x;
    if (i < n) {
        float d = deg[i];
        float r = d > 0.0f ? rsqrtf(d) : 0.0f;
        dinv[i] = r;
        dinv2[i] = r * r;
    }
}

__global__ void k_norm(const int* __restrict__ src, const int* __restrict__ dst,
                       const float* __restrict__ dinv, float* __restrict__ nrm, int e) {
    int i = blockIdx.x * blockDim.x + threadIdx.x;
    if (i < e) nrm[i] = dinv[src[i]] * dinv[dst[i]];
}

// C[M x Ntot](col block bn, width BN) = A[M x 128] * W[128 x Ntot]
// BM=64, full K=128 staged in LDS. 256 threads, each computes a 4x4 micro-tile.
template <int BN, bool RELU_A>
__global__ __launch_bounds__(256) void k_gemm(const float* __restrict__ A,
                                              const float* __restrict__ W,
                                              float* __restrict__ C, int M, int Ntot) {
    __shared__ float As[64][132];   // +4 pad: float4-aligned rows, bank-spread for column reads
    __shared__ float Bs[128][BN];

    const int tid = threadIdx.x;
    const int bm = blockIdx.x * 64;
    const int bn = blockIdx.y * BN;

    // Load W tile: 128 x BN
    constexpr int WF4 = 128 * BN / 4;
    for (int idx = tid; idx < WF4; idx += 256) {
        int row = idx / (BN / 4);
        int c4 = idx % (BN / 4);
        float4 v = *(const float4*)&W[row * Ntot + bn + c4 * 4];
        *(float4*)&Bs[row][c4 * 4] = v;
    }
    // Load A tile: 64 x 128 (guard M tail), optional ReLU on load
    for (int idx = tid; idx < 64 * 32; idx += 256) {
        int row = idx >> 5;
        int c4 = idx & 31;
        int gr = bm + row;
        float4 v = make_float4(0.f, 0.f, 0.f, 0.f);
        if (gr < M) v = *(const float4*)&A[gr * 128 + c4 * 4];
        if (RELU_A) {
            v.x = fmaxf(v.x, 0.f); v.y = fmaxf(v.y, 0.f);
            v.z = fmaxf(v.z, 0.f); v.w = fmaxf(v.w, 0.f);
        }
        *(float4*)&As[row][c4 * 4] = v;
    }
    __syncthreads();

    const int ty = tid >> 4;   // 0..15 -> row group
    const int tx = tid & 15;   // 0..15 -> col group
    float acc[4][4] = {};

    for (int k = 0; k < 128; k += 4) {
        float av[4][4], bv[4][4];
#pragma unroll
        for (int i = 0; i < 4; ++i) {
            float4 t = *(const float4*)&As[ty * 4 + i][k];
            av[i][0] = t.x; av[i][1] = t.y; av[i][2] = t.z; av[i][3] = t.w;
        }
#pragma unroll
        for (int kk = 0; kk < 4; ++kk) {
            float4 t = *(const float4*)&Bs[k + kk][tx * 4];
            bv[kk][0] = t.x; bv[kk][1] = t.y; bv[kk][2] = t.z; bv[kk][3] = t.w;
        }
#pragma unroll
        for (int i = 0; i < 4; ++i)
#pragma unroll
            for (int kk = 0; kk < 4; ++kk)
#pragma unroll
                for (int j = 0; j < 4; ++j)
                    acc[i][j] = fmaf(av[i][kk], bv[kk][j], acc[i][j]);
    }

#pragma unroll
    for (int i = 0; i < 4; ++i) {
        int gr = bm + ty * 4 + i;
        if (gr < M) {
            float4 v = make_float4(acc[i][0], acc[i][1], acc[i][2], acc[i][3]);
            *(float4*)&C[gr * Ntot + bn + tx * 4] = v;
        }
    }
}

// agg[i][c] = h[i][c] * dinv2[i] + b[c]   (self-loop term + bias), float4 per thread
template <int C>
__global__ void k_init_agg(const float* __restrict__ h, const float* __restrict__ dinv2,
                           const float* __restrict__ b, float* __restrict__ agg, int n) {
    constexpr int CP4 = C / 4;
    int g = blockIdx.x * blockDim.x + threadIdx.x;
    if (g < n * CP4) {
        int row = g / CP4;
        int c4 = g % CP4;
        float s = dinv2[row];
        float4 v = *(const float4*)&h[row * C + c4 * 4];
        float4 bb = *(const float4*)&b[c4 * 4];
        float4 o;
        o.x = fmaf(v.x, s, bb.x); o.y = fmaf(v.y, s, bb.y);
        o.z = fmaf(v.z, s, bb.z); o.w = fmaf(v.w, s, bb.w);
        *(float4*)&agg[row * C + c4 * 4] = o;
    }
}

// agg[dst[e]][c] += h[src[e]][c] * norm[e]; C/4 threads per edge, float4 gather.
template <int C>
__global__ void k_scatter(const float* __restrict__ h, const int* __restrict__ src,
                          const int* __restrict__ dst, const float* __restrict__ nrm,
                          float* __restrict__ agg, int e) {
    constexpr int CP4 = C / 4;
    int g = blockIdx.x * blockDim.x + threadIdx.x;
    int eid = g / CP4;
    int c4 = g % CP4;
    if (eid < e) {
        int s = src[eid];
        int d = dst[eid];
        float nm = nrm[eid];
        float4 v = *(const float4*)&h[s * C + c4 * 4];
        float* o = &agg[d * C + c4 * 4];
        atomicAdd(o + 0, v.x * nm);
        atomicAdd(o + 1, v.y * nm);
        atomicAdd(o + 2, v.z * nm);
        atomicAdd(o + 3, v.w * nm);
    }
}

extern "C" void kernel_launch(void* const* d_in, const int* in_sizes, int n_in,
                              void* d_out, int out_size, void* d_ws, size_t ws_size,
                              hipStream_t stream) {
    const float* x  = (const float*)d_in[0];
    const int*   ei = (const int*)d_in[1];   // [2][E] row-major
    const float* W1 = (const float*)d_in[2];
    const float* b1 = (const float*)d_in[3];
    const float* W2 = (const float*)d_in[4];
    const float* b2 = (const float*)d_in[5];
    float* out = (float*)d_out;

    const int N = in_sizes[0] / 128;   // 50000
    const int E = in_sizes[1] / 2;     // 800000
    const int* src = ei;
    const int* dst = ei + E;

    float* ws    = (float*)d_ws;
    float* deg   = ws;                 // N
    float* dinv  = deg + N;            // N
    float* dinv2 = dinv + N;           // N
    float* nrm   = dinv2 + N;          // E
    float* h1    = nrm + E;            // N*128
    float* agg1  = h1 + (size_t)N * 128;  // N*128
    float* h2    = agg1 + (size_t)N * 128; // N*64

    const int B = 256;

    // normalization
    k_init_deg<<<(N + B - 1) / B, B, 0, stream>>>(deg, N);
    k_deg_accum<<<(E + B - 1) / B, B, 0, stream>>>(dst, deg, E);
    k_dinv<<<(N + B - 1) / B, B, 0, stream>>>(deg, dinv, dinv2, N);
    k_norm<<<(E + B - 1) / B, B, 0, stream>>>(src, dst, dinv, nrm, E);

    const int gm = (N + 63) / 64;

    // layer 1: h1 = x @ W1 ; agg1 = scatter(h1) + b1
    k_gemm<64, false><<<dim3(gm, 2), 256, 0, stream>>>(x, W1, h1, N, 128);
    k_init_agg<128><<<((N * 32) + B - 1) / B, B, 0, stream>>>(h1, dinv2, b1, agg1, N);
    k_scatter<128><<<((E * 32) + B - 1) / B, B, 0, stream>>>(h1, src, dst, nrm, agg1, E);

    // layer 2: h2 = relu(agg1) @ W2 ; out = scatter(h2) + b2
    k_gemm<64, true><<<dim3(gm, 1), 256, 0, stream>>>(agg1, W2, h2, N, 64);
    k_init_agg<64><<<((N * 16) + B - 1) / B, B, 0, stream>>>(h2, dinv2, b2, out, N);
    k_scatter<64><<<((E * 16) + B - 1) / B, B, 0, stream>>>(h2, src, dst, nrm, out, E);
}

// Round 2
// 362.728 us; speedup vs baseline: 5.9042x; 5.9042x over previous
//
#include <hip/hip_runtime.h>
#include <hip/hip_bf16.h>

// N_NODES=50000, N_EDGES=800000, IN=128, HID=128, OUT=64, fp32.
// Strategy: device-built CSR (by dst) -> atomic-free per-node aggregation.

__global__ void k_count(const int* __restrict__ dst, int* __restrict__ cnt, int e) {
    int i = blockIdx.x * blockDim.x + threadIdx.x;
    if (i < e) atomicAdd(&cnt[dst[i]], 1);
}

// Single-block chunked exclusive scan (n=50000 -> 49 chunks of 1024).
__global__ __launch_bounds__(1024) void k_scan(const int* __restrict__ cnt,
                                               int* __restrict__ offs,
                                               int* __restrict__ cursor, int n) {
    __shared__ int buf[1024];
    __shared__ int carry_s;
    int tid = threadIdx.x;
    if (tid == 0) carry_s = 0;
    __syncthreads();
    for (int base = 0; base < n; base += 1024) {
        int i = base + tid;
        int v = (i < n) ? cnt[i] : 0;
        buf[tid] = v;
        __syncthreads();
        for (int s = 1; s < 1024; s <<= 1) {
            int t = (tid >= s) ? buf[tid - s] : 0;
            __syncthreads();
            buf[tid] += t;
            __syncthreads();
        }
        int incl = buf[tid];
        int carry = carry_s;
        int excl = incl - v + carry;
        __syncthreads();                 // everyone has read carry_s
        if (tid == 1023) carry_s = carry + incl;
        if (i < n) { offs[i] = excl; cursor[i] = excl; }
        __syncthreads();
    }
    if (tid == 0) offs[n] = carry_s;
}

// deg = cnt + 1 (self-loop); dinv = rsqrt(deg); dinv2 = 1/deg
__global__ void k_dinv(const int* __restrict__ cnt, float* __restrict__ dinv,
                       float* __restrict__ dinv2, int n) {
    int i = blockIdx.x * blockDim.x + threadIdx.x;
    if (i < n) {
        float d = (float)(cnt[i] + 1);
        float r = rsqrtf(d);
        dinv[i] = r;
        dinv2[i] = r * r;
    }
}

// Scatter edges into CSR slots: pairs[pos] = (src, norm)
__global__ void k_fill(const int* __restrict__ src, const int* __restrict__ dst,
                       const float* __restrict__ dinv, int* __restrict__ cursor,
                       int2* __restrict__ pairs, int e) {
    int i = blockIdx.x * blockDim.x + threadIdx.x;
    if (i < e) {
        int s = src[i];
        int d = dst[i];
        float nm = dinv[s] * dinv[d];
        int pos = atomicAdd(&cursor[d], 1);
        pairs[pos] = make_int2(s, __float_as_int(nm));
    }
}

// C[M x Ntot] = A[M x 128] * W[128 x Ntot]; BM=64, full K in LDS.
template <int BN, bool RELU_A>
__global__ __launch_bounds__(256) void k_gemm(const float* __restrict__ A,
                                              const float* __restrict__ W,
                                              float* __restrict__ C, int M, int Ntot) {
    __shared__ float As[64][132];
    __shared__ float Bs[128][BN];

    const int tid = threadIdx.x;
    const int bm = blockIdx.x * 64;
    const int bn = blockIdx.y * BN;

    constexpr int WF4 = 128 * BN / 4;
    for (int idx = tid; idx < WF4; idx += 256) {
        int row = idx / (BN / 4);
        int c4 = idx % (BN / 4);
        float4 v = *(const float4*)&W[row * Ntot + bn + c4 * 4];
        *(float4*)&Bs[row][c4 * 4] = v;
    }
    for (int idx = tid; idx < 64 * 32; idx += 256) {
        int row = idx >> 5;
        int c4 = idx & 31;
        int gr = bm + row;
        float4 v = make_float4(0.f, 0.f, 0.f, 0.f);
        if (gr < M) v = *(const float4*)&A[gr * 128 + c4 * 4];
        if (RELU_A) {
            v.x = fmaxf(v.x, 0.f); v.y = fmaxf(v.y, 0.f);
            v.z = fmaxf(v.z, 0.f); v.w = fmaxf(v.w, 0.f);
        }
        *(float4*)&As[row][c4 * 4] = v;
    }
    __syncthreads();

    const int ty = tid >> 4;
    const int tx = tid & 15;
    float acc[4][4] = {};

    for (int k = 0; k < 128; k += 4) {
        float av[4][4], bv[4][4];
#pragma unroll
        for (int i = 0; i < 4; ++i) {
            float4 t = *(const float4*)&As[ty * 4 + i][k];
            av[i][0] = t.x; av[i][1] = t.y; av[i][2] = t.z; av[i][3] = t.w;
        }
#pragma unroll
        for (int kk = 0; kk < 4; ++kk) {
            float4 t = *(const float4*)&Bs[k + kk][tx * 4];
            bv[kk][0] = t.x; bv[kk][1] = t.y; bv[kk][2] = t.z; bv[kk][3] = t.w;
        }
#pragma unroll
        for (int i = 0; i < 4; ++i)
#pragma unroll
            for (int kk = 0; kk < 4; ++kk)
#pragma unroll
                for (int j = 0; j < 4; ++j)
                    acc[i][j] = fmaf(av[i][kk], bv[kk][j], acc[i][j]);
    }

#pragma unroll
    for (int i = 0; i < 4; ++i) {
        int gr = bm + ty * 4 + i;
        if (gr < M) {
            float4 v = make_float4(acc[i][0], acc[i][1], acc[i][2], acc[i][3]);
            *(float4*)&C[gr * Ntot + bn + tx * 4] = v;
        }
    }
}

// One wave per node: out[i] = b + dinv2[i]*h[i] + sum_e norm_e * h[src_e]
template <int C>
__global__ __launch_bounds__(256) void k_aggr(const float* __restrict__ h,
                                              const int2* __restrict__ pairs,
                                              const int* __restrict__ offs,
                                              const float* __restrict__ dinv2,
                                              const float* __restrict__ bias,
                                              float* __restrict__ out, int n) {
    constexpr int PL = C / 64;           // floats per lane (2 or 1)
    const int lane = threadIdx.x & 63;
    const int wid = threadIdx.x >> 6;
    const int node = blockIdx.x * 4 + wid;
    if (node >= n) return;
    const int col = lane * PL;

    float acc[PL];
    float s2 = dinv2[node];
    if (PL == 2) {
        float2 hv = *(const float2*)&h[(size_t)node * C + col];
        float2 bb = *(const float2*)&bias[col];
        acc[0] = fmaf(hv.x, s2, bb.x);
        acc[1] = fmaf(hv.y, s2, bb.y);
    } else {
        acc[0] = fmaf(h[(size_t)node * C + col], s2, bias[col]);
    }

    const int off = offs[node], end = offs[node + 1];
    for (int base = off; base < end; base += 64) {
        int m = end - base;
        int2 p = make_int2(0, 0);
        if (lane < m) p = pairs[base + lane];
        int cnt = m < 64 ? m : 64;
        for (int j = 0; j < cnt; ++j) {
            int s = __shfl(p.x, j);
            float nm = __shfl(__int_as_float(p.y), j);
            if (PL == 2) {
                float2 hv = *(const float2*)&h[(size_t)s * C + col];
                acc[0] = fmaf(hv.x, nm, acc[0]);
                acc[1] = fmaf(hv.y, nm, acc[1]);
            } else {
                acc[0] = fmaf(h[(size_t)s * C + col], nm, acc[0]);
            }
        }
    }

    if (PL == 2) {
        *(float2*)&out[(size_t)node * C + col] = make_float2(acc[0], acc[1]);
    } else {
        out[(size_t)node * C + col] = acc[0];
    }
}

extern "C" void kernel_launch(void* const* d_in, const int* in_sizes, int n_in,
                              void* d_out, int out_size, void* d_ws, size_t ws_size,
                              hipStream_t stream) {
    const float* x  = (const float*)d_in[0];
    const int*   ei = (const int*)d_in[1];
    const float* W1 = (const float*)d_in[2];
    const float* b1 = (const float*)d_in[3];
    const float* W2 = (const float*)d_in[4];
    const float* b2 = (const float*)d_in[5];
    float* out = (float*)d_out;

    const int N = in_sizes[0] / 128;   // 50000
    const int E = in_sizes[1] / 2;     // 800000
    const int* src = ei;
    const int* dst = ei + E;

    // workspace layout (4-byte units, pairs 8B-aligned)
    char* wsb = (char*)d_ws;
    size_t o = 0;
    auto alloc = [&](size_t bytes, size_t align) {
        o = (o + align - 1) & ~(align - 1);
        char* p = wsb + o;
        o += bytes;
        return p;
    };
    int*   cnt    = (int*)alloc((size_t)N * 4, 4);
    int*   offs   = (int*)alloc((size_t)(N + 1) * 4, 4);
    int*   cursor = (int*)alloc((size_t)N * 4, 4);
    float* dinv   = (float*)alloc((size_t)N * 4, 4);
    float* dinv2  = (float*)alloc((size_t)N * 4, 4);
    int2*  pairs  = (int2*)alloc((size_t)E * 8, 8);
    float* h1     = (float*)alloc((size_t)N * 128 * 4, 16);
    float* agg1   = (float*)alloc((size_t)N * 128 * 4, 16);
    float* h2     = h1;   // overlay: h1 dead once agg1 is built

    const int B = 256;

    hipMemsetAsync(cnt, 0, (size_t)N * 4, stream);
    k_count<<<(E + B - 1) / B, B, 0, stream>>>(dst, cnt, E);
    k_scan<<<1, 1024, 0, stream>>>(cnt, offs, cursor, N);
    k_dinv<<<(N + B - 1) / B, B, 0, stream>>>(cnt, dinv, dinv2, N);
    k_fill<<<(E + B - 1) / B, B, 0, stream>>>(src, dst, dinv, cursor, pairs, E);

    const int gm = (N + 63) / 64;
    const int ga = (N + 3) / 4;

    // layer 1
    k_gemm<64, false><<<dim3(gm, 2), 256, 0, stream>>>(x, W1, h1, N, 128);
    k_aggr<128><<<ga, 256, 0, stream>>>(h1, pairs, offs, dinv2, b1, agg1, N);

    // layer 2
    k_gemm<64, true><<<dim3(gm, 1), 256, 0, stream>>>(agg1, W2, h2, N, 64);
    k_aggr<64><<<ga, 256, 0, stream>>>(h2, pairs, offs, dinv2, b2, out, N);
}

// Round 3
// 279.578 us; speedup vs baseline: 7.6602x; 1.2974x over previous
//
#include <hip/hip_runtime.h>
#include <hip/hip_bf16.h>

// N_NODES=50000, N_EDGES=800000, IN=128, HID=128, OUT=64, fp32.
// CSR (by dst) built on device -> atomic-free per-node aggregation.

__global__ void k_count(const int* __restrict__ dst, int* __restrict__ cnt, int e) {
    int i = blockIdx.x * blockDim.x + threadIdx.x;
    if (i < e) atomicAdd(&cnt[dst[i]], 1);
}

// ---- hierarchical exclusive scan over n ints (chunks of 1024) ----
// Phase 1: per-block local exclusive scan + block sum.
__global__ __launch_bounds__(256) void k_scan_blk(const int* __restrict__ cnt,
                                                  int* __restrict__ offs,
                                                  int* __restrict__ blksum, int n) {
    __shared__ int wsum[4];
    const int tid = threadIdx.x;
    const int base = blockIdx.x * 1024 + tid * 4;
    int4 v = make_int4(0, 0, 0, 0);
    if (base + 3 < n) {
        v = *(const int4*)&cnt[base];
    } else {
        if (base + 0 < n) v.x = cnt[base + 0];
        if (base + 1 < n) v.y = cnt[base + 1];
        if (base + 2 < n) v.z = cnt[base + 2];
        if (base + 3 < n) v.w = cnt[base + 3];
    }
    const int t = v.x + v.y + v.z + v.w;
    const int lane = tid & 63;
    const int wid = tid >> 6;
    int s = t;  // inclusive wave scan
#pragma unroll
    for (int d = 1; d < 64; d <<= 1) {
        int u = __shfl_up(s, d);
        if (lane >= d) s += u;
    }
    if (lane == 63) wsum[wid] = s;
    __syncthreads();
    int wcarry = 0;
    for (int w = 0; w < wid; ++w) wcarry += wsum[w];
    const int excl = wcarry + s - t;

    int4 o;
    o.x = excl;
    o.y = o.x + v.x;
    o.z = o.y + v.y;
    o.w = o.z + v.z;
    if (base + 3 < n) {
        *(int4*)&offs[base] = o;
    } else {
        if (base + 0 < n) offs[base + 0] = o.x;
        if (base + 1 < n) offs[base + 1] = o.y;
        if (base + 2 < n) offs[base + 2] = o.z;
        if (base + 3 < n) offs[base + 3] = o.w;
    }
    if (tid == 255) blksum[blockIdx.x] = wcarry + s;  // block total
}

// Phase 2: one wave exclusive-scans the block sums (nblk <= 64*loop).
__global__ __launch_bounds__(64) void k_scan_top(int* __restrict__ blksum, int nblk) {
    const int lane = threadIdx.x;
    int carry = 0;
    for (int base = 0; base < nblk; base += 64) {
        int i = base + lane;
        int v = (i < nblk) ? blksum[i] : 0;
        int s = v;
#pragma unroll
        for (int d = 1; d < 64; d <<= 1) {
            int u = __shfl_up(s, d);
            if (lane >= d) s += u;
        }
        if (i < nblk) blksum[i] = carry + s - v;
        carry += __shfl(s, 63);
    }
}

// Phase 3: add block carries, emit cursor copy, set offs[n]=e.
__global__ __launch_bounds__(256) void k_scan_add(int* __restrict__ offs,
                                                  int* __restrict__ cursor,
                                                  const int* __restrict__ blksum,
                                                  int n, int e) {
    const int tid = threadIdx.x;
    const int base = blockIdx.x * 1024 + tid * 4;
    const int carry = blksum[blockIdx.x];
    if (base + 3 < n) {
        int4 o = *(const int4*)&offs[base];
        o.x += carry; o.y += carry; o.z += carry; o.w += carry;
        *(int4*)&offs[base] = o;
        *(int4*)&cursor[base] = o;
    } else {
        for (int k = 0; k < 4; ++k) {
            if (base + k < n) {
                int o = offs[base + k] + carry;
                offs[base + k] = o;
                cursor[base + k] = o;
            }
        }
    }
    if (blockIdx.x == 0 && tid == 0) offs[n] = e;
}

// deg = cnt + 1 (self-loop); dinv = rsqrt(deg); dinv2 = 1/deg
__global__ void k_dinv(const int* __restrict__ cnt, float* __restrict__ dinv,
                       float* __restrict__ dinv2, int n) {
    int i = blockIdx.x * blockDim.x + threadIdx.x;
    if (i < n) {
        float d = (float)(cnt[i] + 1);
        float r = rsqrtf(d);
        dinv[i] = r;
        dinv2[i] = r * r;
    }
}

// Scatter edges into CSR slots: pairs[pos] = (src, norm)
__global__ void k_fill(const int* __restrict__ src, const int* __restrict__ dst,
                       const float* __restrict__ dinv, int* __restrict__ cursor,
                       int2* __restrict__ pairs, int e) {
    int i = blockIdx.x * blockDim.x + threadIdx.x;
    if (i < e) {
        int s = src[i];
        int d = dst[i];
        float nm = dinv[s] * dinv[d];
        int pos = atomicAdd(&cursor[d], 1);
        pairs[pos] = make_int2(s, __float_as_int(nm));
    }
}

// C[M x Ntot] = A[M x 128] * W[128 x Ntot]; BM=64, full K in LDS.
template <int BN, bool RELU_A>
__global__ __launch_bounds__(256) void k_gemm(const float* __restrict__ A,
                                              const float* __restrict__ W,
                                              float* __restrict__ C, int M, int Ntot) {
    __shared__ float As[64][132];
    __shared__ float Bs[128][BN];

    const int tid = threadIdx.x;
    const int bm = blockIdx.x * 64;
    const int bn = blockIdx.y * BN;

    constexpr int WF4 = 128 * BN / 4;
    for (int idx = tid; idx < WF4; idx += 256) {
        int row = idx / (BN / 4);
        int c4 = idx % (BN / 4);
        float4 v = *(const float4*)&W[row * Ntot + bn + c4 * 4];
        *(float4*)&Bs[row][c4 * 4] = v;
    }
    for (int idx = tid; idx < 64 * 32; idx += 256) {
        int row = idx >> 5;
        int c4 = idx & 31;
        int gr = bm + row;
        float4 v = make_float4(0.f, 0.f, 0.f, 0.f);
        if (gr < M) v = *(const float4*)&A[gr * 128 + c4 * 4];
        if (RELU_A) {
            v.x = fmaxf(v.x, 0.f); v.y = fmaxf(v.y, 0.f);
            v.z = fmaxf(v.z, 0.f); v.w = fmaxf(v.w, 0.f);
        }
        *(float4*)&As[row][c4 * 4] = v;
    }
    __syncthreads();

    const int ty = tid >> 4;
    const int tx = tid & 15;
    float acc[4][4] = {};

    for (int k = 0; k < 128; k += 4) {
        float av[4][4], bv[4][4];
#pragma unroll
        for (int i = 0; i < 4; ++i) {
            float4 t = *(const float4*)&As[ty * 4 + i][k];
            av[i][0] = t.x; av[i][1] = t.y; av[i][2] = t.z; av[i][3] = t.w;
        }
#pragma unroll
        for (int kk = 0; kk < 4; ++kk) {
            float4 t = *(const float4*)&Bs[k + kk][tx * 4];
            bv[kk][0] = t.x; bv[kk][1] = t.y; bv[kk][2] = t.z; bv[kk][3] = t.w;
        }
#pragma unroll
        for (int i = 0; i < 4; ++i)
#pragma unroll
            for (int kk = 0; kk < 4; ++kk)
#pragma unroll
                for (int j = 0; j < 4; ++j)
                    acc[i][j] = fmaf(av[i][kk], bv[kk][j], acc[i][j]);
    }

#pragma unroll
    for (int i = 0; i < 4; ++i) {
        int gr = bm + ty * 4 + i;
        if (gr < M) {
            float4 v = make_float4(acc[i][0], acc[i][1], acc[i][2], acc[i][3]);
            *(float4*)&C[gr * Ntot + bn + tx * 4] = v;
        }
    }
}

// One wave per node: out[i] = b + dinv2[i]*h[i] + sum_e norm_e * h[src_e]
template <int C>
__global__ __launch_bounds__(256) void k_aggr(const float* __restrict__ h,
                                              const int2* __restrict__ pairs,
                                              const int* __restrict__ offs,
                                              const float* __restrict__ dinv2,
                                              const float* __restrict__ bias,
                                              float* __restrict__ out, int n) {
    constexpr int PL = C / 64;           // floats per lane (2 or 1)
    const int lane = threadIdx.x & 63;
    const int wid = threadIdx.x >> 6;
    const int node = blockIdx.x * 4 + wid;
    if (node >= n) return;
    const int col = lane * PL;

    float acc[PL];
    float s2 = dinv2[node];
    if (PL == 2) {
        float2 hv = *(const float2*)&h[(size_t)node * C + col];
        float2 bb = *(const float2*)&bias[col];
        acc[0] = fmaf(hv.x, s2, bb.x);
        acc[1] = fmaf(hv.y, s2, bb.y);
    } else {
        acc[0] = fmaf(h[(size_t)node * C + col], s2, bias[col]);
    }

    const int off = offs[node], end = offs[node + 1];
    for (int base = off; base < end; base += 64) {
        int m = end - base;
        int2 p = make_int2(0, 0);
        if (lane < m) p = pairs[base + lane];
        int cnt = m < 64 ? m : 64;
        for (int j = 0; j < cnt; ++j) {
            int s = __shfl(p.x, j);
            float nm = __shfl(__int_as_float(p.y), j);
            if (PL == 2) {
                float2 hv = *(const float2*)&h[(size_t)s * C + col];
                acc[0] = fmaf(hv.x, nm, acc[0]);
                acc[1] = fmaf(hv.y, nm, acc[1]);
            } else {
                acc[0] = fmaf(h[(size_t)s * C + col], nm, acc[0]);
            }
        }
    }

    if (PL == 2) {
        *(float2*)&out[(size_t)node * C + col] = make_float2(acc[0], acc[1]);
    } else {
        out[(size_t)node * C + col] = acc[0];
    }
}

extern "C" void kernel_launch(void* const* d_in, const int* in_sizes, int n_in,
                              void* d_out, int out_size, void* d_ws, size_t ws_size,
                              hipStream_t stream) {
    const float* x  = (const float*)d_in[0];
    const int*   ei = (const int*)d_in[1];
    const float* W1 = (const float*)d_in[2];
    const float* b1 = (const float*)d_in[3];
    const float* W2 = (const float*)d_in[4];
    const float* b2 = (const float*)d_in[5];
    float* out = (float*)d_out;

    const int N = in_sizes[0] / 128;   // 50000
    const int E = in_sizes[1] / 2;     // 800000
    const int* src = ei;
    const int* dst = ei + E;

    char* wsb = (char*)d_ws;
    size_t o = 0;
    auto alloc = [&](size_t bytes, size_t align) {
        o = (o + align - 1) & ~(align - 1);
        char* p = wsb + o;
        o += bytes;
        return p;
    };
    const int nblk = (N + 1023) / 1024;
    int*   cnt    = (int*)alloc((size_t)N * 4, 4);
    int*   offs   = (int*)alloc((size_t)(N + 1) * 4, 4);
    int*   cursor = (int*)alloc((size_t)N * 4, 4);
    int*   blksum = (int*)alloc((size_t)nblk * 4, 4);
    float* dinv   = (float*)alloc((size_t)N * 4, 4);
    float* dinv2  = (float*)alloc((size_t)N * 4, 4);
    int2*  pairs  = (int2*)alloc((size_t)E * 8, 8);
    float* h1     = (float*)alloc((size_t)N * 128 * 4, 16);
    float* agg1   = (float*)alloc((size_t)N * 128 * 4, 16);
    float* h2     = h1;   // overlay: h1 dead once agg1 built

    const int B = 256;

    hipMemsetAsync(cnt, 0, (size_t)N * 4, stream);
    k_count<<<(E + B - 1) / B, B, 0, stream>>>(dst, cnt, E);
    k_scan_blk<<<nblk, 256, 0, stream>>>(cnt, offs, blksum, N);
    k_scan_top<<<1, 64, 0, stream>>>(blksum, nblk);
    k_scan_add<<<nblk, 256, 0, stream>>>(offs, cursor, blksum, N, E);
    k_dinv<<<(N + B - 1) / B, B, 0, stream>>>(cnt, dinv, dinv2, N);
    k_fill<<<(E + B - 1) / B, B, 0, stream>>>(src, dst, dinv, cursor, pairs, E);

    const int gm = (N + 63) / 64;
    const int ga = (N + 3) / 4;

    // layer 1
    k_gemm<64, false><<<dim3(gm, 2), 256, 0, stream>>>(x, W1, h1, N, 128);
    k_aggr<128><<<ga, 256, 0, stream>>>(h1, pairs, offs, dinv2, b1, agg1, N);

    // layer 2
    k_gemm<64, true><<<dim3(gm, 1), 256, 0, stream>>>(agg1, W2, h2, N, 64);
    k_aggr<64><<<ga, 256, 0, stream>>>(h2, pairs, offs, dinv2, b2, out, N);
}

// Round 4
// 256.277 us; speedup vs baseline: 8.3567x; 1.0909x over previous
//
#include <hip/hip_runtime.h>
#include <hip/hip_bf16.h>

// N_NODES=50000, N_EDGES=800000, IN=128, HID=128, OUT=64, fp32.
// CSR (by dst) built on device -> atomic-free per-node aggregation.

__global__ void k_count(const int* __restrict__ dst, int* __restrict__ cnt, int e) {
    int i = blockIdx.x * blockDim.x + threadIdx.x;
    if (i < e) atomicAdd(&cnt[dst[i]], 1);
}

// ---- hierarchical exclusive scan over n ints (chunks of 1024) ----
__global__ __launch_bounds__(256) void k_scan_blk(const int* __restrict__ cnt,
                                                  int* __restrict__ offs,
                                                  int* __restrict__ blksum, int n) {
    __shared__ int wsum[4];
    const int tid = threadIdx.x;
    const int base = blockIdx.x * 1024 + tid * 4;
    int4 v = make_int4(0, 0, 0, 0);
    if (base + 3 < n) {
        v = *(const int4*)&cnt[base];
    } else {
        if (base + 0 < n) v.x = cnt[base + 0];
        if (base + 1 < n) v.y = cnt[base + 1];
        if (base + 2 < n) v.z = cnt[base + 2];
        if (base + 3 < n) v.w = cnt[base + 3];
    }
    const int t = v.x + v.y + v.z + v.w;
    const int lane = tid & 63;
    const int wid = tid >> 6;
    int s = t;
#pragma unroll
    for (int d = 1; d < 64; d <<= 1) {
        int u = __shfl_up(s, d);
        if (lane >= d) s += u;
    }
    if (lane == 63) wsum[wid] = s;
    __syncthreads();
    int wcarry = 0;
    for (int w = 0; w < wid; ++w) wcarry += wsum[w];
    const int excl = wcarry + s - t;

    int4 o;
    o.x = excl;
    o.y = o.x + v.x;
    o.z = o.y + v.y;
    o.w = o.z + v.z;
    if (base + 3 < n) {
        *(int4*)&offs[base] = o;
    } else {
        if (base + 0 < n) offs[base + 0] = o.x;
        if (base + 1 < n) offs[base + 1] = o.y;
        if (base + 2 < n) offs[base + 2] = o.z;
        if (base + 3 < n) offs[base + 3] = o.w;
    }
    if (tid == 255) blksum[blockIdx.x] = wcarry + s;
}

__global__ __launch_bounds__(64) void k_scan_top(int* __restrict__ blksum, int nblk) {
    const int lane = threadIdx.x;
    int carry = 0;
    for (int base = 0; base < nblk; base += 64) {
        int i = base + lane;
        int v = (i < nblk) ? blksum[i] : 0;
        int s = v;
#pragma unroll
        for (int d = 1; d < 64; d <<= 1) {
            int u = __shfl_up(s, d);
            if (lane >= d) s += u;
        }
        if (i < nblk) blksum[i] = carry + s - v;
        carry += __shfl(s, 63);
    }
}

__global__ __launch_bounds__(256) void k_scan_add(int* __restrict__ offs,
                                                  int* __restrict__ cursor,
                                                  const int* __restrict__ blksum,
                                                  int n, int e) {
    const int tid = threadIdx.x;
    const int base = blockIdx.x * 1024 + tid * 4;
    const int carry = blksum[blockIdx.x];
    if (base + 3 < n) {
        int4 o = *(const int4*)&offs[base];
        o.x += carry; o.y += carry; o.z += carry; o.w += carry;
        *(int4*)&offs[base] = o;
        *(int4*)&cursor[base] = o;
    } else {
        for (int k = 0; k < 4; ++k) {
            if (base + k < n) {
                int o = offs[base + k] + carry;
                offs[base + k] = o;
                cursor[base + k] = o;
            }
        }
    }
    if (blockIdx.x == 0 && tid == 0) offs[n] = e;
}

__global__ void k_dinv(const int* __restrict__ cnt, float* __restrict__ dinv,
                       float* __restrict__ dinv2, int n) {
    int i = blockIdx.x * blockDim.x + threadIdx.x;
    if (i < n) {
        float d = (float)(cnt[i] + 1);
        float r = rsqrtf(d);
        dinv[i] = r;
        dinv2[i] = r * r;
    }
}

__global__ void k_fill(const int* __restrict__ src, const int* __restrict__ dst,
                       const float* __restrict__ dinv, int* __restrict__ cursor,
                       int2* __restrict__ pairs, int e) {
    int i = blockIdx.x * blockDim.x + threadIdx.x;
    if (i < e) {
        int s = src[i];
        int d = dst[i];
        float nm = dinv[s] * dinv[d];
        int pos = atomicAdd(&cursor[d], 1);
        pairs[pos] = make_int2(s, __float_as_int(nm));
    }
}

// C[M x Ntot] = A[M x 128] * W[128 x Ntot]; BM=64, full K in LDS.
template <int BN, bool RELU_A>
__global__ __launch_bounds__(256) void k_gemm(const float* __restrict__ A,
                                              const float* __restrict__ W,
                                              float* __restrict__ C, int M, int Ntot) {
    __shared__ float As[64][132];
    __shared__ float Bs[128][BN];

    const int tid = threadIdx.x;
    const int bm = blockIdx.x * 64;
    const int bn = blockIdx.y * BN;

    constexpr int WF4 = 128 * BN / 4;
    for (int idx = tid; idx < WF4; idx += 256) {
        int row = idx / (BN / 4);
        int c4 = idx % (BN / 4);
        float4 v = *(const float4*)&W[row * Ntot + bn + c4 * 4];
        *(float4*)&Bs[row][c4 * 4] = v;
    }
    for (int idx = tid; idx < 64 * 32; idx += 256) {
        int row = idx >> 5;
        int c4 = idx & 31;
        int gr = bm + row;
        float4 v = make_float4(0.f, 0.f, 0.f, 0.f);
        if (gr < M) v = *(const float4*)&A[gr * 128 + c4 * 4];
        if (RELU_A) {
            v.x = fmaxf(v.x, 0.f); v.y = fmaxf(v.y, 0.f);
            v.z = fmaxf(v.z, 0.f); v.w = fmaxf(v.w, 0.f);
        }
        *(float4*)&As[row][c4 * 4] = v;
    }
    __syncthreads();

    const int ty = tid >> 4;
    const int tx = tid & 15;
    float acc[4][4] = {};

    for (int k = 0; k < 128; k += 4) {
        float av[4][4], bv[4][4];
#pragma unroll
        for (int i = 0; i < 4; ++i) {
            float4 t = *(const float4*)&As[ty * 4 + i][k];
            av[i][0] = t.x; av[i][1] = t.y; av[i][2] = t.z; av[i][3] = t.w;
        }
#pragma unroll
        for (int kk = 0; kk < 4; ++kk) {
            float4 t = *(const float4*)&Bs[k + kk][tx * 4];
            bv[kk][0] = t.x; bv[kk][1] = t.y; bv[kk][2] = t.z; bv[kk][3] = t.w;
        }
#pragma unroll
        for (int i = 0; i < 4; ++i)
#pragma unroll
            for (int kk = 0; kk < 4; ++kk)
#pragma unroll
                for (int j = 0; j < 4; ++j)
                    acc[i][j] = fmaf(av[i][kk], bv[kk][j], acc[i][j]);
    }

#pragma unroll
    for (int i = 0; i < 4; ++i) {
        int gr = bm + ty * 4 + i;
        if (gr < M) {
            float4 v = make_float4(acc[i][0], acc[i][1], acc[i][2], acc[i][3]);
            *(float4*)&C[gr * Ntot + bn + tx * 4] = v;
        }
    }
}

// One wave per node: out[i] = b + dinv2[i]*h[i] + sum_e norm_e * h[src_e]
// Inner loop batched x8: 8 gathers in flight to hide load latency.
template <int C>
__global__ __launch_bounds__(256) void k_aggr(const float* __restrict__ h,
                                              const int2* __restrict__ pairs,
                                              const int* __restrict__ offs,
                                              const float* __restrict__ dinv2,
                                              const float* __restrict__ bias,
                                              float* __restrict__ out, int n) {
    constexpr int PL = C / 64;           // floats per lane (2 or 1)
    const int lane = threadIdx.x & 63;
    const int wid = threadIdx.x >> 6;
    const int node = blockIdx.x * 4 + wid;
    if (node >= n) return;
    const int col = lane * PL;

    float acc[PL];
    float s2 = dinv2[node];
    if (PL == 2) {
        float2 hv = *(const float2*)&h[(size_t)node * C + col];
        float2 bb = *(const float2*)&bias[col];
        acc[0] = fmaf(hv.x, s2, bb.x);
        acc[1] = fmaf(hv.y, s2, bb.y);
    } else {
        acc[0] = fmaf(h[(size_t)node * C + col], s2, bias[col]);
    }

    const int off = offs[node], end = offs[node + 1];
    for (int base = off; base < end; base += 64) {
        int m = end - base;
        int2 p = make_int2(0, 0);            // pad: s=0, nm=0.0 -> exact no-op
        if (lane < m) p = pairs[base + lane];
        int cnt = m < 64 ? m : 64;
        int cntR = (cnt + 7) & ~7;           // round up to unroll factor

        for (int j0 = 0; j0 < cntR; j0 += 8) {
            int   sA[8];
            float nmA[8];
#pragma unroll
            for (int jj = 0; jj < 8; ++jj) {
                sA[jj] = __shfl(p.x, j0 + jj);
                nmA[jj] = __shfl(__int_as_float(p.y), j0 + jj);
            }
            if (PL == 2) {
                float2 hv[8];
#pragma unroll
                for (int jj = 0; jj < 8; ++jj)
                    hv[jj] = *(const float2*)&h[(size_t)sA[jj] * C + col];
#pragma unroll
                for (int jj = 0; jj < 8; ++jj) {
                    acc[0] = fmaf(hv[jj].x, nmA[jj], acc[0]);
                    acc[1] = fmaf(hv[jj].y, nmA[jj], acc[1]);
                }
            } else {
                float hv[8];
#pragma unroll
                for (int jj = 0; jj < 8; ++jj)
                    hv[jj] = h[(size_t)sA[jj] * C + col];
#pragma unroll
                for (int jj = 0; jj < 8; ++jj)
                    acc[0] = fmaf(hv[jj], nmA[jj], acc[0]);
            }
        }
    }

    if (PL == 2) {
        *(float2*)&out[(size_t)node * C + col] = make_float2(acc[0], acc[1]);
    } else {
        out[(size_t)node * C + col] = acc[0];
    }
}

extern "C" void kernel_launch(void* const* d_in, const int* in_sizes, int n_in,
                              void* d_out, int out_size, void* d_ws, size_t ws_size,
                              hipStream_t stream) {
    const float* x  = (const float*)d_in[0];
    const int*   ei = (const int*)d_in[1];
    const float* W1 = (const float*)d_in[2];
    const float* b1 = (const float*)d_in[3];
    const float* W2 = (const float*)d_in[4];
    const float* b2 = (const float*)d_in[5];
    float* out = (float*)d_out;

    const int N = in_sizes[0] / 128;   // 50000
    const int E = in_sizes[1] / 2;     // 800000
    const int* src = ei;
    const int* dst = ei + E;

    char* wsb = (char*)d_ws;
    size_t o = 0;
    auto alloc = [&](size_t bytes, size_t align) {
        o = (o + align - 1) & ~(align - 1);
        char* p = wsb + o;
        o += bytes;
        return p;
    };
    const int nblk = (N + 1023) / 1024;
    int*   cnt    = (int*)alloc((size_t)N * 4, 4);
    int*   offs   = (int*)alloc((size_t)(N + 1) * 4, 4);
    int*   cursor = (int*)alloc((size_t)N * 4, 4);
    int*   blksum = (int*)alloc((size_t)nblk * 4, 4);
    float* dinv   = (float*)alloc((size_t)N * 4, 4);
    float* dinv2  = (float*)alloc((size_t)N * 4, 4);
    int2*  pairs  = (int2*)alloc((size_t)E * 8, 8);
    float* h1     = (float*)alloc((size_t)N * 128 * 4, 16);
    float* agg1   = (float*)alloc((size_t)N * 128 * 4, 16);
    float* h2     = h1;   // overlay: h1 dead once agg1 built

    const int B = 256;

    hipMemsetAsync(cnt, 0, (size_t)N * 4, stream);
    k_count<<<(E + B - 1) / B, B, 0, stream>>>(dst, cnt, E);
    k_scan_blk<<<nblk, 256, 0, stream>>>(cnt, offs, blksum, N);
    k_scan_top<<<1, 64, 0, stream>>>(blksum, nblk);
    k_scan_add<<<nblk, 256, 0, stream>>>(offs, cursor, blksum, N, E);
    k_dinv<<<(N + B - 1) / B, B, 0, stream>>>(cnt, dinv, dinv2, N);
    k_fill<<<(E + B - 1) / B, B, 0, stream>>>(src, dst, dinv, cursor, pairs, E);

    const int gm = (N + 63) / 64;
    const int ga = (N + 3) / 4;

    // layer 1
    k_gemm<64, false><<<dim3(gm, 2), 256, 0, stream>>>(x, W1, h1, N, 128);
    k_aggr<128><<<ga, 256, 0, stream>>>(h1, pairs, offs, dinv2, b1, agg1, N);

    // layer 2
    k_gemm<64, true><<<dim3(gm, 1), 256, 0, stream>>>(agg1, W2, h2, N, 64);
    k_aggr<64><<<ga, 256, 0, stream>>>(h2, pairs, offs, dinv2, b2, out, N);
}

// Round 5
// 253.326 us; speedup vs baseline: 8.4540x; 1.0116x over previous
//
#include <hip/hip_runtime.h>
#include <hip/hip_bf16.h>

// N_NODES=50000, N_EDGES=800000, IN=128, HID=128, OUT=64, fp32.
// CSR (by dst) built on device -> atomic-free per-node aggregation.
// Aggregation gathers are float4-wide with multiple edges packed per wave-load.

__global__ void k_count(const int* __restrict__ dst, int* __restrict__ cnt, int e) {
    int i = blockIdx.x * blockDim.x + threadIdx.x;
    if (i < e) atomicAdd(&cnt[dst[i]], 1);
}

// ---- hierarchical exclusive scan over n ints (chunks of 1024) ----
__global__ __launch_bounds__(256) void k_scan_blk(const int* __restrict__ cnt,
                                                  int* __restrict__ offs,
                                                  int* __restrict__ blksum, int n) {
    __shared__ int wsum[4];
    const int tid = threadIdx.x;
    const int base = blockIdx.x * 1024 + tid * 4;
    int4 v = make_int4(0, 0, 0, 0);
    if (base + 3 < n) {
        v = *(const int4*)&cnt[base];
    } else {
        if (base + 0 < n) v.x = cnt[base + 0];
        if (base + 1 < n) v.y = cnt[base + 1];
        if (base + 2 < n) v.z = cnt[base + 2];
        if (base + 3 < n) v.w = cnt[base + 3];
    }
    const int t = v.x + v.y + v.z + v.w;
    const int lane = tid & 63;
    const int wid = tid >> 6;
    int s = t;
#pragma unroll
    for (int d = 1; d < 64; d <<= 1) {
        int u = __shfl_up(s, d);
        if (lane >= d) s += u;
    }
    if (lane == 63) wsum[wid] = s;
    __syncthreads();
    int wcarry = 0;
    for (int w = 0; w < wid; ++w) wcarry += wsum[w];
    const int excl = wcarry + s - t;

    int4 o;
    o.x = excl;
    o.y = o.x + v.x;
    o.z = o.y + v.y;
    o.w = o.z + v.z;
    if (base + 3 < n) {
        *(int4*)&offs[base] = o;
    } else {
        if (base + 0 < n) offs[base + 0] = o.x;
        if (base + 1 < n) offs[base + 1] = o.y;
        if (base + 2 < n) offs[base + 2] = o.z;
        if (base + 3 < n) offs[base + 3] = o.w;
    }
    if (tid == 255) blksum[blockIdx.x] = wcarry + s;
}

__global__ __launch_bounds__(64) void k_scan_top(int* __restrict__ blksum, int nblk) {
    const int lane = threadIdx.x;
    int carry = 0;
    for (int base = 0; base < nblk; base += 64) {
        int i = base + lane;
        int v = (i < nblk) ? blksum[i] : 0;
        int s = v;
#pragma unroll
        for (int d = 1; d < 64; d <<= 1) {
            int u = __shfl_up(s, d);
            if (lane >= d) s += u;
        }
        if (i < nblk) blksum[i] = carry + s - v;
        carry += __shfl(s, 63);
    }
}

__global__ __launch_bounds__(256) void k_scan_add(int* __restrict__ offs,
                                                  int* __restrict__ cursor,
                                                  const int* __restrict__ blksum,
                                                  int n, int e) {
    const int tid = threadIdx.x;
    const int base = blockIdx.x * 1024 + tid * 4;
    const int carry = blksum[blockIdx.x];
    if (base + 3 < n) {
        int4 o = *(const int4*)&offs[base];
        o.x += carry; o.y += carry; o.z += carry; o.w += carry;
        *(int4*)&offs[base] = o;
        *(int4*)&cursor[base] = o;
    } else {
        for (int k = 0; k < 4; ++k) {
            if (base + k < n) {
                int o = offs[base + k] + carry;
                offs[base + k] = o;
                cursor[base + k] = o;
            }
        }
    }
    if (blockIdx.x == 0 && tid == 0) offs[n] = e;
}

__global__ void k_dinv(const int* __restrict__ cnt, float* __restrict__ dinv,
                       float* __restrict__ dinv2, int n) {
    int i = blockIdx.x * blockDim.x + threadIdx.x;
    if (i < n) {
        float d = (float)(cnt[i] + 1);
        float r = rsqrtf(d);
        dinv[i] = r;
        dinv2[i] = r * r;
    }
}

__global__ void k_fill(const int* __restrict__ src, const int* __restrict__ dst,
                       const float* __restrict__ dinv, int* __restrict__ cursor,
                       int2* __restrict__ pairs, int e) {
    int i = blockIdx.x * blockDim.x + threadIdx.x;
    if (i < e) {
        int s = src[i];
        int d = dst[i];
        float nm = dinv[s] * dinv[d];
        int pos = atomicAdd(&cursor[d], 1);
        pairs[pos] = make_int2(s, __float_as_int(nm));
    }
}

// C[M x Ntot] = A[M x 128] * W[128 x Ntot]; BM=64, full K in LDS.
template <int BN, bool RELU_A>
__global__ __launch_bounds__(256) void k_gemm(const float* __restrict__ A,
                                              const float* __restrict__ W,
                                              float* __restrict__ C, int M, int Ntot) {
    __shared__ float As[64][132];
    __shared__ float Bs[128][BN];

    const int tid = threadIdx.x;
    const int bm = blockIdx.x * 64;
    const int bn = blockIdx.y * BN;

    constexpr int WF4 = 128 * BN / 4;
    for (int idx = tid; idx < WF4; idx += 256) {
        int row = idx / (BN / 4);
        int c4 = idx % (BN / 4);
        float4 v = *(const float4*)&W[row * Ntot + bn + c4 * 4];
        *(float4*)&Bs[row][c4 * 4] = v;
    }
    for (int idx = tid; idx < 64 * 32; idx += 256) {
        int row = idx >> 5;
        int c4 = idx & 31;
        int gr = bm + row;
        float4 v = make_float4(0.f, 0.f, 0.f, 0.f);
        if (gr < M) v = *(const float4*)&A[gr * 128 + c4 * 4];
        if (RELU_A) {
            v.x = fmaxf(v.x, 0.f); v.y = fmaxf(v.y, 0.f);
            v.z = fmaxf(v.z, 0.f); v.w = fmaxf(v.w, 0.f);
        }
        *(float4*)&As[row][c4 * 4] = v;
    }
    __syncthreads();

    const int ty = tid >> 4;
    const int tx = tid & 15;
    float acc[4][4] = {};

    for (int k = 0; k < 128; k += 4) {
        float av[4][4], bv[4][4];
#pragma unroll
        for (int i = 0; i < 4; ++i) {
            float4 t = *(const float4*)&As[ty * 4 + i][k];
            av[i][0] = t.x; av[i][1] = t.y; av[i][2] = t.z; av[i][3] = t.w;
        }
#pragma unroll
        for (int kk = 0; kk < 4; ++kk) {
            float4 t = *(const float4*)&Bs[k + kk][tx * 4];
            bv[kk][0] = t.x; bv[kk][1] = t.y; bv[kk][2] = t.z; bv[kk][3] = t.w;
        }
#pragma unroll
        for (int i = 0; i < 4; ++i)
#pragma unroll
            for (int kk = 0; kk < 4; ++kk)
#pragma unroll
                for (int j = 0; j < 4; ++j)
                    acc[i][j] = fmaf(av[i][kk], bv[kk][j], acc[i][j]);
    }

#pragma unroll
    for (int i = 0; i < 4; ++i) {
        int gr = bm + ty * 4 + i;
        if (gr < M) {
            float4 v = make_float4(acc[i][0], acc[i][1], acc[i][2], acc[i][3]);
            *(float4*)&C[gr * Ntot + bn + tx * 4] = v;
        }
    }
}

// One wave per node. float4 per lane; EPG edges packed per wave-load:
//   C=128: 32 lanes/row, 2 edges/load; C=64: 16 lanes/row, 4 edges/load.
// Each lane accumulates its edge-group; shfl_xor reduction merges groups.
template <int C>
__global__ __launch_bounds__(256) void k_aggr(const float* __restrict__ h,
                                              const int2* __restrict__ pairs,
                                              const int* __restrict__ offs,
                                              const float* __restrict__ dinv2,
                                              const float* __restrict__ bias,
                                              float* __restrict__ out, int n) {
    constexpr int LPR = C / 4;        // lanes per row: 32 or 16
    constexpr int EPG = 64 / LPR;     // edges per gather: 2 or 4
    constexpr int STEP = 8 * EPG;     // edges per unrolled batch
    const int lane = threadIdx.x & 63;
    const int wid = threadIdx.x >> 6;
    const int node = blockIdx.x * 4 + wid;
    if (node >= n) return;
    const int sub = lane & (LPR - 1);
    const int grp = lane / LPR;
    const int col = sub * 4;

    float4 acc = make_float4(0.f, 0.f, 0.f, 0.f);

    const int off = offs[node], end = offs[node + 1];
    for (int base = off; base < end; base += 64) {
        int m = end - base;
        int2 p = make_int2(0, 0);            // pad: s=0, nm=0.0 -> exact no-op
        if (lane < m) p = pairs[base + lane];
        int cnt = m < 64 ? m : 64;
        int cntR = (cnt + STEP - 1) & ~(STEP - 1);   // <= 64

        for (int j0 = 0; j0 < cntR; j0 += STEP) {
            int   sA[8];
            float nmA[8];
#pragma unroll
            for (int k = 0; k < 8; ++k) {
                int e = j0 + k * EPG + grp;   // per-lane edge slot
                sA[k] = __shfl(p.x, e);
                nmA[k] = __shfl(__int_as_float(p.y), e);
            }
            float4 hv[8];
#pragma unroll
            for (int k = 0; k < 8; ++k)
                hv[k] = *(const float4*)&h[(size_t)sA[k] * C + col];
#pragma unroll
            for (int k = 0; k < 8; ++k) {
                acc.x = fmaf(hv[k].x, nmA[k], acc.x);
                acc.y = fmaf(hv[k].y, nmA[k], acc.y);
                acc.z = fmaf(hv[k].z, nmA[k], acc.z);
                acc.w = fmaf(hv[k].w, nmA[k], acc.w);
            }
        }
    }

    // merge edge-groups: lanes differing in bits >= log2(LPR) hold same cols
#pragma unroll
    for (int d = LPR; d < 64; d <<= 1) {
        acc.x += __shfl_xor(acc.x, d);
        acc.y += __shfl_xor(acc.y, d);
        acc.z += __shfl_xor(acc.z, d);
        acc.w += __shfl_xor(acc.w, d);
    }

    if (grp == 0) {
        float s2 = dinv2[node];
        float4 hv = *(const float4*)&h[(size_t)node * C + col];
        float4 bb = *(const float4*)&bias[col];
        acc.x = fmaf(hv.x, s2, acc.x + bb.x);
        acc.y = fmaf(hv.y, s2, acc.y + bb.y);
        acc.z = fmaf(hv.z, s2, acc.z + bb.z);
        acc.w = fmaf(hv.w, s2, acc.w + bb.w);
        *(float4*)&out[(size_t)node * C + col] = acc;
    }
}

extern "C" void kernel_launch(void* const* d_in, const int* in_sizes, int n_in,
                              void* d_out, int out_size, void* d_ws, size_t ws_size,
                              hipStream_t stream) {
    const float* x  = (const float*)d_in[0];
    const int*   ei = (const int*)d_in[1];
    const float* W1 = (const float*)d_in[2];
    const float* b1 = (const float*)d_in[3];
    const float* W2 = (const float*)d_in[4];
    const float* b2 = (const float*)d_in[5];
    float* out = (float*)d_out;

    const int N = in_sizes[0] / 128;   // 50000
    const int E = in_sizes[1] / 2;     // 800000
    const int* src = ei;
    const int* dst = ei + E;

    char* wsb = (char*)d_ws;
    size_t o = 0;
    auto alloc = [&](size_t bytes, size_t align) {
        o = (o + align - 1) & ~(align - 1);
        char* p = wsb + o;
        o += bytes;
        return p;
    };
    const int nblk = (N + 1023) / 1024;
    int*   cnt    = (int*)alloc((size_t)N * 4, 4);
    int*   offs   = (int*)alloc((size_t)(N + 1) * 4, 4);
    int*   cursor = (int*)alloc((size_t)N * 4, 4);
    int*   blksum = (int*)alloc((size_t)nblk * 4, 4);
    float* dinv   = (float*)alloc((size_t)N * 4, 4);
    float* dinv2  = (float*)alloc((size_t)N * 4, 4);
    int2*  pairs  = (int2*)alloc((size_t)E * 8, 8);
    float* h1     = (float*)alloc((size_t)N * 128 * 4, 16);
    float* agg1   = (float*)alloc((size_t)N * 128 * 4, 16);
    float* h2     = h1;   // overlay: h1 dead once agg1 built

    const int B = 256;

    hipMemsetAsync(cnt, 0, (size_t)N * 4, stream);
    k_count<<<(E + B - 1) / B, B, 0, stream>>>(dst, cnt, E);
    k_scan_blk<<<nblk, 256, 0, stream>>>(cnt, offs, blksum, N);
    k_scan_top<<<1, 64, 0, stream>>>(blksum, nblk);
    k_scan_add<<<nblk, 256, 0, stream>>>(offs, cursor, blksum, N, E);
    k_dinv<<<(N + B - 1) / B, B, 0, stream>>>(cnt, dinv, dinv2, N);
    k_fill<<<(E + B - 1) / B, B, 0, stream>>>(src, dst, dinv, cursor, pairs, E);

    const int gm = (N + 63) / 64;
    const int ga = (N + 3) / 4;

    // layer 1
    k_gemm<64, false><<<dim3(gm, 2), 256, 0, stream>>>(x, W1, h1, N, 128);
    k_aggr<128><<<ga, 256, 0, stream>>>(h1, pairs, offs, dinv2, b1, agg1, N);

    // layer 2
    k_gemm<64, true><<<dim3(gm, 1), 256, 0, stream>>>(agg1, W2, h2, N, 64);
    k_aggr<64><<<ga, 256, 0, stream>>>(h2, pairs, offs, dinv2, b2, out, N);
}

// Round 6
// 214.072 us; speedup vs baseline: 10.0043x; 1.1834x over previous
//
#include <hip/hip_runtime.h>
#include <hip/hip_bf16.h>

// N_NODES=50000, N_EDGES=800000, IN=128, HID=128, OUT=64, fp32 in/out.
// CSR (by dst) on device -> atomic-free aggregation with async global_load_lds
// gathers; h1/h2 stored bf16 (fp32 accumulate) to halve gather traffic.

__device__ __forceinline__ unsigned short f2bf(float f) {
    unsigned int u = __float_as_uint(f);
    unsigned int r = u + 0x7fffu + ((u >> 16) & 1u);   // RNE
    return (unsigned short)(r >> 16);
}

__global__ void k_count(const int* __restrict__ dst, int* __restrict__ cnt, int e) {
    int i = blockIdx.x * blockDim.x + threadIdx.x;
    if (i < e) atomicAdd(&cnt[dst[i]], 1);
}

// ---- hierarchical exclusive scan over n ints (chunks of 1024) ----
__global__ __launch_bounds__(256) void k_scan_blk(const int* __restrict__ cnt,
                                                  int* __restrict__ offs,
                                                  int* __restrict__ blksum, int n) {
    __shared__ int wsum[4];
    const int tid = threadIdx.x;
    const int base = blockIdx.x * 1024 + tid * 4;
    int4 v = make_int4(0, 0, 0, 0);
    if (base + 3 < n) {
        v = *(const int4*)&cnt[base];
    } else {
        if (base + 0 < n) v.x = cnt[base + 0];
        if (base + 1 < n) v.y = cnt[base + 1];
        if (base + 2 < n) v.z = cnt[base + 2];
        if (base + 3 < n) v.w = cnt[base + 3];
    }
    const int t = v.x + v.y + v.z + v.w;
    const int lane = tid & 63;
    const int wid = tid >> 6;
    int s = t;
#pragma unroll
    for (int d = 1; d < 64; d <<= 1) {
        int u = __shfl_up(s, d);
        if (lane >= d) s += u;
    }
    if (lane == 63) wsum[wid] = s;
    __syncthreads();
    int wcarry = 0;
    for (int w = 0; w < wid; ++w) wcarry += wsum[w];
    const int excl = wcarry + s - t;

    int4 o;
    o.x = excl;
    o.y = o.x + v.x;
    o.z = o.y + v.y;
    o.w = o.z + v.z;
    if (base + 3 < n) {
        *(int4*)&offs[base] = o;
    } else {
        if (base + 0 < n) offs[base + 0] = o.x;
        if (base + 1 < n) offs[base + 1] = o.y;
        if (base + 2 < n) offs[base + 2] = o.z;
        if (base + 3 < n) offs[base + 3] = o.w;
    }
    if (tid == 255) blksum[blockIdx.x] = wcarry + s;
}

__global__ __launch_bounds__(64) void k_scan_top(int* __restrict__ blksum, int nblk) {
    const int lane = threadIdx.x;
    int carry = 0;
    for (int base = 0; base < nblk; base += 64) {
        int i = base + lane;
        int v = (i < nblk) ? blksum[i] : 0;
        int s = v;
#pragma unroll
        for (int d = 1; d < 64; d <<= 1) {
            int u = __shfl_up(s, d);
            if (lane >= d) s += u;
        }
        if (i < nblk) blksum[i] = carry + s - v;
        carry += __shfl(s, 63);
    }
}

__global__ __launch_bounds__(256) void k_scan_add(int* __restrict__ offs,
                                                  int* __restrict__ cursor,
                                                  const int* __restrict__ blksum,
                                                  int n, int e) {
    const int tid = threadIdx.x;
    const int base = blockIdx.x * 1024 + tid * 4;
    const int carry = blksum[blockIdx.x];
    if (base + 3 < n) {
        int4 o = *(const int4*)&offs[base];
        o.x += carry; o.y += carry; o.z += carry; o.w += carry;
        *(int4*)&offs[base] = o;
        *(int4*)&cursor[base] = o;
    } else {
        for (int k = 0; k < 4; ++k) {
            if (base + k < n) {
                int o = offs[base + k] + carry;
                offs[base + k] = o;
                cursor[base + k] = o;
            }
        }
    }
    if (blockIdx.x == 0 && tid == 0) offs[n] = e;
}

__global__ void k_dinv(const int* __restrict__ cnt, float* __restrict__ dinv,
                       float* __restrict__ dinv2, int n) {
    int i = blockIdx.x * blockDim.x + threadIdx.x;
    if (i < n) {
        float d = (float)(cnt[i] + 1);
        float r = rsqrtf(d);
        dinv[i] = r;
        dinv2[i] = r * r;
    }
}

__global__ void k_fill(const int* __restrict__ src, const int* __restrict__ dst,
                       const float* __restrict__ dinv, int* __restrict__ cursor,
                       int2* __restrict__ pairs, int e) {
    int i = blockIdx.x * blockDim.x + threadIdx.x;
    if (i < e) {
        int s = src[i];
        int d = dst[i];
        float nm = dinv[s] * dinv[d];
        int pos = atomicAdd(&cursor[d], 1);
        pairs[pos] = make_int2(s, __float_as_int(nm));
    }
}

// C[M x Ntot] = A[M x 128] * W[128 x Ntot]; BM=64, full K in LDS.
// OUTBF: store bf16 output, else fp32.
template <int BN, bool RELU_A, bool OUTBF>
__global__ __launch_bounds__(256) void k_gemm(const float* __restrict__ A,
                                              const float* __restrict__ W,
                                              void* __restrict__ Cout, int M, int Ntot) {
    __shared__ float As[64][132];
    __shared__ float Bs[128][BN];

    const int tid = threadIdx.x;
    const int bm = blockIdx.x * 64;
    const int bn = blockIdx.y * BN;

    constexpr int WF4 = 128 * BN / 4;
    for (int idx = tid; idx < WF4; idx += 256) {
        int row = idx / (BN / 4);
        int c4 = idx % (BN / 4);
        float4 v = *(const float4*)&W[row * Ntot + bn + c4 * 4];
        *(float4*)&Bs[row][c4 * 4] = v;
    }
    for (int idx = tid; idx < 64 * 32; idx += 256) {
        int row = idx >> 5;
        int c4 = idx & 31;
        int gr = bm + row;
        float4 v = make_float4(0.f, 0.f, 0.f, 0.f);
        if (gr < M) v = *(const float4*)&A[gr * 128 + c4 * 4];
        if (RELU_A) {
            v.x = fmaxf(v.x, 0.f); v.y = fmaxf(v.y, 0.f);
            v.z = fmaxf(v.z, 0.f); v.w = fmaxf(v.w, 0.f);
        }
        *(float4*)&As[row][c4 * 4] = v;
    }
    __syncthreads();

    const int ty = tid >> 4;
    const int tx = tid & 15;
    float acc[4][4] = {};

    for (int k = 0; k < 128; k += 4) {
        float av[4][4], bv[4][4];
#pragma unroll
        for (int i = 0; i < 4; ++i) {
            float4 t = *(const float4*)&As[ty * 4 + i][k];
            av[i][0] = t.x; av[i][1] = t.y; av[i][2] = t.z; av[i][3] = t.w;
        }
#pragma unroll
        for (int kk = 0; kk < 4; ++kk) {
            float4 t = *(const float4*)&Bs[k + kk][tx * 4];
            bv[kk][0] = t.x; bv[kk][1] = t.y; bv[kk][2] = t.z; bv[kk][3] = t.w;
        }
#pragma unroll
        for (int i = 0; i < 4; ++i)
#pragma unroll
            for (int kk = 0; kk < 4; ++kk)
#pragma unroll
                for (int j = 0; j < 4; ++j)
                    acc[i][j] = fmaf(av[i][kk], bv[kk][j], acc[i][j]);
    }

#pragma unroll
    for (int i = 0; i < 4; ++i) {
        int gr = bm + ty * 4 + i;
        if (gr < M) {
            if (OUTBF) {
                ushort4 o;
                o.x = f2bf(acc[i][0]); o.y = f2bf(acc[i][1]);
                o.z = f2bf(acc[i][2]); o.w = f2bf(acc[i][3]);
                *(ushort4*)&((unsigned short*)Cout)[(size_t)gr * Ntot + bn + tx * 4] = o;
            } else {
                float4 v = make_float4(acc[i][0], acc[i][1], acc[i][2], acc[i][3]);
                *(float4*)&((float*)Cout)[(size_t)gr * Ntot + bn + tx * 4] = v;
            }
        }
    }
}

// One wave per node, h in bf16. Gathers go global->LDS asynchronously
// (global_load_lds, per-lane global addr, zero VGPR cost), then FMA from LDS.
template <int C>
__global__ __launch_bounds__(256) void k_aggr(const unsigned short* __restrict__ hb,
                                              const int2* __restrict__ pairs,
                                              const int* __restrict__ offs,
                                              const float* __restrict__ dinv2,
                                              const float* __restrict__ bias,
                                              float* __restrict__ outp, int n) {
    constexpr int ROWB = C * 2;            // bf16 row bytes: 256 or 128
    constexpr int LPE  = ROWB / 16;        // lanes per row in a 1KB load: 16 or 8
    constexpr int EPL  = 64 / LPE;         // edge rows per 1KB load: 4 or 8
    constexpr int CHUNK = 16;              // edges per chunk
    __shared__ __align__(1024) char smem[4][CHUNK * ROWB];

    const int lane = threadIdx.x & 63;
    const int wid  = threadIdx.x >> 6;
    const int node = blockIdx.x * 4 + wid;
    if (node >= n) return;
    char* region = smem[wid];

    float2 acc = make_float2(0.f, 0.f);

    const int off = offs[node], end = offs[node + 1];
    for (int base = off; base < end; base += 64) {
        const int m = end - base;
        int2 p = make_int2(0, 0);           // pad lanes: row 0, nm 0
        if (lane < m) p = pairs[base + lane];
        const int cnt = m < 64 ? m : 64;

        for (int j0 = 0; j0 < cnt; j0 += CHUNK) {
            const int cc = min(CHUNK, cnt - j0);
            const int nload = (cc + EPL - 1) / EPL;
            // issue async gathers: each 1KB load = EPL rows, 16B/lane
            for (int l = 0; l < nload; ++l) {
                int e = j0 + l * EPL + (lane / LPE);     // e <= 63
                int srow = __shfl(p.x, e);               // pad lanes -> row 0
                const char* ga = (const char*)hb + (size_t)srow * ROWB + (lane % LPE) * 16;
                __builtin_amdgcn_global_load_lds(
                    (const __attribute__((address_space(1))) unsigned int*)ga,
                    (__attribute__((address_space(3))) unsigned int*)(region + l * 1024),
                    16, 0, 0);
            }
            asm volatile("s_waitcnt vmcnt(0)" ::: "memory");
            __builtin_amdgcn_sched_barrier(0);

            if (C == 128) {
                // full row per wave: lane holds cols {2*lane, 2*lane+1}
                for (int j = 0; j < cc; ++j) {
                    float nm = __shfl(__int_as_float(p.y), j0 + j);
                    unsigned int u = *(const unsigned int*)(region + j * ROWB + lane * 4);
                    float lo = __uint_as_float(u << 16);
                    float hi = __uint_as_float(u & 0xffff0000u);
                    acc.x = fmaf(lo, nm, acc.x);
                    acc.y = fmaf(hi, nm, acc.y);
                }
            } else {
                // two rows per round: half-wave each; lane holds cols {2*(l&31), +1}
                const int half = lane >> 5;
                const int rounds = (cc + 1) >> 1;
                for (int r = 0; r < rounds; ++r) {
                    int e = r * 2 + half;
                    float nm = __shfl(__int_as_float(p.y), j0 + (e < cc ? e : 0));
                    unsigned int u = *(const unsigned int*)(region + e * ROWB + (lane & 31) * 4);
                    if (e >= cc) { nm = 0.f; u = 0u; }
                    float lo = __uint_as_float(u << 16);
                    float hi = __uint_as_float(u & 0xffff0000u);
                    acc.x = fmaf(lo, nm, acc.x);
                    acc.y = fmaf(hi, nm, acc.y);
                }
            }
        }
    }

    if (C == 128) {
        float s2 = dinv2[node];
        unsigned int u = *(const unsigned int*)((const char*)hb + (size_t)node * ROWB + lane * 4);
        float lo = __uint_as_float(u << 16);
        float hi = __uint_as_float(u & 0xffff0000u);
        float2 bb = *(const float2*)&bias[lane * 2];
        acc.x = fmaf(lo, s2, acc.x + bb.x);
        acc.y = fmaf(hi, s2, acc.y + bb.y);
        *(float2*)&outp[(size_t)node * C + lane * 2] = acc;
    } else {
        acc.x += __shfl_xor(acc.x, 32);
        acc.y += __shfl_xor(acc.y, 32);
        if (lane < 32) {
            float s2 = dinv2[node];
            unsigned int u = *(const unsigned int*)((const char*)hb + (size_t)node * ROWB + lane * 4);
            float lo = __uint_as_float(u << 16);
            float hi = __uint_as_float(u & 0xffff0000u);
            float2 bb = *(const float2*)&bias[lane * 2];
            acc.x = fmaf(lo, s2, acc.x + bb.x);
            acc.y = fmaf(hi, s2, acc.y + bb.y);
            *(float2*)&outp[(size_t)node * C + lane * 2] = acc;
        }
    }
}

extern "C" void kernel_launch(void* const* d_in, const int* in_sizes, int n_in,
                              void* d_out, int out_size, void* d_ws, size_t ws_size,
                              hipStream_t stream) {
    const float* x  = (const float*)d_in[0];
    const int*   ei = (const int*)d_in[1];
    const float* W1 = (const float*)d_in[2];
    const float* b1 = (const float*)d_in[3];
    const float* W2 = (const float*)d_in[4];
    const float* b2 = (const float*)d_in[5];
    float* out = (float*)d_out;

    const int N = in_sizes[0] / 128;   // 50000
    const int E = in_sizes[1] / 2;     // 800000
    const int* src = ei;
    const int* dst = ei + E;

    char* wsb = (char*)d_ws;
    size_t o = 0;
    auto alloc = [&](size_t bytes, size_t align) {
        o = (o + align - 1) & ~(align - 1);
        char* p = wsb + o;
        o += bytes;
        return p;
    };
    const int nblk = (N + 1023) / 1024;
    int*   cnt    = (int*)alloc((size_t)N * 4, 4);
    int*   offs   = (int*)alloc((size_t)(N + 1) * 4, 4);
    int*   cursor = (int*)alloc((size_t)N * 4, 4);
    int*   blksum = (int*)alloc((size_t)nblk * 4, 4);
    float* dinv   = (float*)alloc((size_t)N * 4, 4);
    float* dinv2  = (float*)alloc((size_t)N * 4, 4);
    int2*  pairs  = (int2*)alloc((size_t)E * 8, 8);
    unsigned short* h1b = (unsigned short*)alloc((size_t)N * 128 * 2, 16);
    unsigned short* h2b = (unsigned short*)alloc((size_t)N * 64 * 2, 16);
    float* agg1   = (float*)alloc((size_t)N * 128 * 4, 16);

    const int B = 256;

    hipMemsetAsync(cnt, 0, (size_t)N * 4, stream);
    k_count<<<(E + B - 1) / B, B, 0, stream>>>(dst, cnt, E);
    k_scan_blk<<<nblk, 256, 0, stream>>>(cnt, offs, blksum, N);
    k_scan_top<<<1, 64, 0, stream>>>(blksum, nblk);
    k_scan_add<<<nblk, 256, 0, stream>>>(offs, cursor, blksum, N, E);
    k_dinv<<<(N + B - 1) / B, B, 0, stream>>>(cnt, dinv, dinv2, N);
    k_fill<<<(E + B - 1) / B, B, 0, stream>>>(src, dst, dinv, cursor, pairs, E);

    const int gm = (N + 63) / 64;
    const int ga = (N + 3) / 4;

    // layer 1: h1b(bf16) = x @ W1 ; agg1(fp32) = aggregate(h1b) + b1
    k_gemm<64, false, true><<<dim3(gm, 2), 256, 0, stream>>>(x, W1, h1b, N, 128);
    k_aggr<128><<<ga, 256, 0, stream>>>(h1b, pairs, offs, dinv2, b1, agg1, N);

    // layer 2: h2b(bf16) = relu(agg1) @ W2 ; out(fp32) = aggregate(h2b) + b2
    k_gemm<64, true, true><<<dim3(gm, 1), 256, 0, stream>>>(agg1, W2, h2b, N, 64);
    k_aggr<64><<<ga, 256, 0, stream>>>(h2b, pairs, offs, dinv2, b2, out, N);
}